// Round 6
// baseline (579.833 us; speedup 1.0000x reference)
//
#include <hip/hip_runtime.h>
#include <stdint.h>

typedef unsigned long long ull;
typedef unsigned int u32;

#define NPGC 512
#define EPGC 4096
#define NTHREADS 512
#define ETOT 4194304
#define NEGF (-1e30f)

__global__ __launch_bounds__(NTHREADS, 6)
void gce_kernel(const float* __restrict__ x,
                const float* __restrict__ Wc,
                const float* __restrict__ bc,
                const float* __restrict__ pvec,
                const float* __restrict__ Wg,
                const float* __restrict__ bg,
                const int* __restrict__ ei,
                float* __restrict__ out)
{
    __shared__ float  A[8][NPGC];              // 16 KB conv acc (P2-P4); P5: hist/hoff/wsum
    __shared__ float4 Blo[NPGC];               //  8 KB node-major features ch 0-3
    __shared__ float4 Bhi[NPGC];               //  8 KB node-major features ch 4-7
    __shared__ float  maskf[NPGC];             //  2 KB
    __shared__ float  degv[NPGC];              //  2 KB deg->dinv; later comp16+chmax
    __shared__ __align__(16) ull keyv[NPGC];   //  4 KB bin-sorted records; P7: r1/r2
    // total exactly 40960 B -> 4 blocks/CU

    const int tid  = threadIdx.x;
    const int lane = tid & 63;      // also the attention channel
    const int g    = blockIdx.x;
    const int grp  = tid >> 6;      // wave id (0..7)

    unsigned short* comp16 = reinterpret_cast<unsigned short*>(degv);  // bytes [0,1024)
    float* chmax = degv + 256;                                         // bytes [1024,1280)
    float* r1 = reinterpret_cast<float*>(keyv);                        // [8][64] = 2 KB
    float* r2 = r1 + 512;                                              // [8][64] = 2 KB
    u32* hist = reinterpret_cast<u32*>(A);     // words [0,512)    (A dead in P5)
    u32* hoff = hist + 512;                    // words [512,1024)
    u32* wsum = hist + 1024;                   // words [1024,1032)

    float wgc[8];
#pragma unroll
    for (int j = 0; j < 8; ++j) wgc[j] = Wg[j * 64 + lane];
    const float bgc = bg[lane];

    // ---- preload this thread's 8 edges, packed (row | col<<16), local ids
    uint32_t er[8];
    {
        const int* rowp = ei;
        const int* colp = ei + ETOT;
        const size_t eb = (size_t)g * EPGC + (size_t)tid * 8;
#pragma unroll
        for (int i = 0; i < 2; ++i) {
            int4 r4 = *reinterpret_cast<const int4*>(rowp + eb + i * 4);
            int4 c4 = *reinterpret_cast<const int4*>(colp + eb + i * 4);
            er[i * 4 + 0] = (uint32_t)(r4.x & 511) | ((uint32_t)(c4.x & 511) << 16);
            er[i * 4 + 1] = (uint32_t)(r4.y & 511) | ((uint32_t)(c4.y & 511) << 16);
            er[i * 4 + 2] = (uint32_t)(r4.z & 511) | ((uint32_t)(c4.z & 511) << 16);
            er[i * 4 + 3] = (uint32_t)(r4.w & 511) | ((uint32_t)(c4.w & 511) << 16);
        }
    }

    // ---- load x into node-major B, mask = 1
    {
        const float* xr = x + ((size_t)g * NPGC + tid) * 8;
        Blo[tid] = *reinterpret_cast<const float4*>(xr);
        Bhi[tid] = *reinterpret_cast<const float4*>(xr + 4);
        maskf[tid] = 1.0f;
    }

    int   kkprev  = NPGC;   // count of valid nodes entering this layer
    float out_acc = 0.f;

#pragma unroll 1
    for (int layer = 0; layer < 4; ++layer) {
        const float* Wl = Wc + layer * 64;
        const float* bl = bc + layer * 8;
        const float* pl = pvec + layer * 8;
        const int kk = (layer == 0) ? 410 : (layer == 1) ? 328 : (layer == 2) ? 263 : 211;

        __syncthreads();                 // B/maskf ready; degv/keyv/A regions free
        const float mf = maskf[tid];
        degv[tid] = mf;
        __syncthreads();

        // ---- P1: B <- B @ W (in place) ; degree atomics ; cache edge validity
        if (mf > 0.f) {
            const float4 lo = Blo[tid], hi = Bhi[tid];
            const float hv[8] = {lo.x, lo.y, lo.z, lo.w, hi.x, hi.y, hi.z, hi.w};
            float yv[8];
#pragma unroll
            for (int k = 0; k < 8; ++k) {
                float acc = 0.f;
#pragma unroll
                for (int j = 0; j < 8; ++j) acc += hv[j] * Wl[j * 8 + k];
                yv[k] = acc;
            }
            Blo[tid] = make_float4(yv[0], yv[1], yv[2], yv[3]);
            Bhi[tid] = make_float4(yv[4], yv[5], yv[6], yv[7]);
        }
        u32 vb = 0;
#pragma unroll
        for (int i = 0; i < 8; ++i) {
            const int rl = er[i] & 0xffff, cl = er[i] >> 16;
            if (maskf[rl] > 0.f && maskf[cl] > 0.f) {
                atomicAdd(&degv[cl], 1.0f);
                vb |= (1u << i);
            }
        }
        __syncthreads();

        // ---- P2: dinv ; A <- self-loop term (valid nodes)
        {
            const float dg = degv[tid];
            const float di = (dg > 0.f) ? rsqrtf(dg) : 0.f;
            degv[tid] = di;              // own slot
            if (mf > 0.f) {
                const float c0 = di * di;
                const float4 lo = Blo[tid], hi = Bhi[tid];
                A[0][tid] = lo.x * c0; A[1][tid] = lo.y * c0;
                A[2][tid] = lo.z * c0; A[3][tid] = lo.w * c0;
                A[4][tid] = hi.x * c0; A[5][tid] = hi.y * c0;
                A[6][tid] = hi.z * c0; A[7][tid] = hi.w * c0;
            }
        }
        __syncthreads();

        // ---- P3: edge scatter (validity-gated)  A[:,col] += B[row]*dinv[row]*dinv[col]
#pragma unroll
        for (int i = 0; i < 8; ++i) {
            if ((vb >> i) & 1u) {
                const int rl = er[i] & 0xffff, cl = er[i] >> 16;
                const float nrm = degv[rl] * degv[cl];
                const float4 lo = Blo[rl], hi = Bhi[rl];
                atomicAdd(&A[0][cl], lo.x * nrm);
                atomicAdd(&A[1][cl], lo.y * nrm);
                atomicAdd(&A[2][cl], lo.z * nrm);
                atomicAdd(&A[3][cl], lo.w * nrm);
                atomicAdd(&A[4][cl], hi.x * nrm);
                atomicAdd(&A[5][cl], hi.y * nrm);
                atomicAdd(&A[6][cl], hi.z * nrm);
                atomicAdd(&A[7][cl], hi.w * nrm);
            }
        }
        __syncthreads();

        // ---- P4: (+bias)*mask, relu -> B ; score ; key code + bin (regs only)
        float s0 = 0.f;
        u32 code0 = 0;
        int bin0 = 0;
        ull rec0 = 0;
        {
            float pv[8], ss = 0.f;
#pragma unroll
            for (int k = 0; k < 8; ++k) { pv[k] = pl[k]; ss += pv[k] * pv[k]; }
            const float pn = sqrtf(ss);
            float v[8], dot = 0.f;
#pragma unroll
            for (int k = 0; k < 8; ++k) {
                float t = (A[k][tid] + bl[k]) * mf;   // reads A (before hist clobbers it)
                t = fmaxf(t, 0.f);
                v[k] = t;
                dot += t * pv[k];
            }
            Blo[tid] = make_float4(v[0], v[1], v[2], v[3]);
            Bhi[tid] = make_float4(v[4], v[5], v[6], v[7]);
            s0 = tanhf(dot / pn);
            const unsigned ub  = __float_as_uint(s0);
            const unsigned asc = (ub & 0x80000000u) ? ~ub : (ub | 0x80000000u);
            code0 = ~asc;                              // ascending = descending score
            rec0  = ((ull)code0 << 32) | (u32)tid;     // tie-break: node index asc
            int b = (int)((1.0f - s0) * 256.0f);       // monotone with code0
            bin0 = (b < 0) ? 0 : ((b > 511) ? 511 : b);
        }
        __syncthreads();                 // all A reads done -> hist may reuse A

        // ---- P5: exact histogram rank
        hist[tid] = 0u;
        hoff[tid] = 0u;
        __syncthreads();
        if (mf > 0.f) atomicAdd(&hist[bin0], 1u);
        __syncthreads();
        {   // block exclusive prefix-sum over 512 bins
            const u32 hv = hist[tid];
            u32 sc = hv;
#pragma unroll
            for (int d = 1; d < 64; d <<= 1) {
                const u32 t = __shfl_up(sc, (unsigned)d, 64);
                if (lane >= d) sc += t;
            }
            if (lane == 63) wsum[grp] = sc;
            __syncthreads();
            u32 woff = 0;
#pragma unroll
            for (int w = 0; w < 7; ++w) woff += (w < grp) ? wsum[w] : 0u;
            hist[tid] = sc + woff - hv;  // exclusive cum (own slot, post-barrier)
        }
        __syncthreads();
        u32 base = 0, nxt = 0;
        if (mf > 0.f) {
            base = hist[bin0];
            nxt  = (bin0 < 511) ? hist[bin0 + 1] : (u32)kkprev;
            const u32 pos = base + atomicAdd(&hoff[bin0], 1u);
            keyv[pos] = rec0;            // order within bin irrelevant (count below)
        }
        __syncthreads();
        u32 rank = 0xFFFFFFFFu;
        if (mf > 0.f) {
            u32 r = base;
            for (u32 j = base; j < nxt; ++j) r += (keyv[j] < rec0) ? 1u : 0u;
            rank = r;
        }

        // ---- P6: keep top-k, scale B, compacted node list (deterministic)
        if (mf > 0.f) {
            if (rank < (u32)kk) {
                comp16[rank] = (unsigned short)tid;
                float4 lo = Blo[tid], hi = Bhi[tid];
                lo.x *= s0; lo.y *= s0; lo.z *= s0; lo.w *= s0;
                hi.x *= s0; hi.y *= s0; hi.z *= s0; hi.w *= s0;
                Blo[tid] = lo; Bhi[tid] = hi;
            } else {
                maskf[tid] = 0.f;        // B self-heals to 0 next layer via mf
            }
        }
        __syncthreads();

        // ---- P7: attention pool, online softmax, 2-way ILP, vector gate reads
        {
            float m = NEGF, esum = 0.f, wsum2 = 0.f;
            int i = grp;
            for (; i + 8 < kk; i += 16) {
                const int na = comp16[i];
                const int nb = comp16[i + 8];
                const float4 alo = Blo[na], ahi = Bhi[na];   // broadcast b128
                const float4 blo = Blo[nb], bhi = Bhi[nb];
                float ga = bgc, gb = bgc;
                ga += alo.x * wgc[0] + alo.y * wgc[1] + alo.z * wgc[2] + alo.w * wgc[3];
                ga += ahi.x * wgc[4] + ahi.y * wgc[5] + ahi.z * wgc[6] + ahi.w * wgc[7];
                gb += blo.x * wgc[0] + blo.y * wgc[1] + blo.z * wgc[2] + blo.w * wgc[3];
                gb += bhi.x * wgc[4] + bhi.y * wgc[5] + bhi.z * wgc[6] + bhi.w * wgc[7];
                const float mn = fmaxf(m, fmaxf(ga, gb));
                const float sc = __expf(m - mn);
                const float ea = __expf(ga - mn);
                const float eb = __expf(gb - mn);
                esum  = esum * sc + ea + eb;
                wsum2 = wsum2 * sc + ea * ga + eb * gb;
                m = mn;
            }
            if (i < kk) {
                const int na = comp16[i];
                const float4 alo = Blo[na], ahi = Bhi[na];
                float ga = bgc;
                ga += alo.x * wgc[0] + alo.y * wgc[1] + alo.z * wgc[2] + alo.w * wgc[3];
                ga += ahi.x * wgc[4] + ahi.y * wgc[5] + ahi.z * wgc[6] + ahi.w * wgc[7];
                const float mn = fmaxf(m, ga);
                const float sc = __expf(m - mn);
                const float ea = __expf(ga - mn);
                esum  = esum * sc + ea;
                wsum2 = wsum2 * sc + ea * ga;
                m = mn;
            }
            r1[grp * 64 + lane] = m;
            __syncthreads();
            if (tid < 64) {
                float M = r1[tid];
#pragma unroll
                for (int w = 1; w < 8; ++w) M = fmaxf(M, r1[w * 64 + tid]);
                chmax[tid] = M;
            }
            __syncthreads();
            const float M  = chmax[lane];
            const float sc = __expf(m - M);
            r1[grp * 64 + lane] = esum * sc;
            r2[grp * 64 + lane] = wsum2 * sc;
            __syncthreads();
            if (tid < 64) {
                float es = 0.f, ws = 0.f;
#pragma unroll
                for (int w = 0; w < 8; ++w) { es += r1[w * 64 + tid]; ws += r2[w * 64 + tid]; }
                out_acc += ws / es;
            }
        }

        kkprev = kk;
    }

    if (tid < 64) out[(size_t)g * 64 + tid] = out_acc;
}

extern "C" void kernel_launch(void* const* d_in, const int* in_sizes, int n_in,
                              void* d_out, int out_size, void* d_ws, size_t ws_size,
                              hipStream_t stream) {
    const float* x    = (const float*)d_in[0];
    const float* Wc   = (const float*)d_in[1];
    const float* bc   = (const float*)d_in[2];
    const float* pvec = (const float*)d_in[3];
    const float* Wg   = (const float*)d_in[4];
    const float* bg   = (const float*)d_in[5];
    const int*   ei   = (const int*)d_in[6];
    float* out = (float*)d_out;

    gce_kernel<<<dim3(1024), dim3(NTHREADS), 0, stream>>>(x, Wc, bc, pvec, Wg, bg, ei, out);
}

// Round 7
// 153.921 us; speedup vs baseline: 3.7671x; 3.7671x over previous
//
#include <hip/hip_runtime.h>
#include <stdint.h>

typedef unsigned long long ull;
typedef unsigned int u32;
typedef unsigned short u16;

#define NPGC 512
#define EPGC 4096
#define NTHREADS 512
#define ETOT 4194304
#define NEGF (-1e30f)

__global__ __launch_bounds__(NTHREADS, 6)
void gce_kernel(const float* __restrict__ x,
                const float* __restrict__ Wc,
                const float* __restrict__ bc,
                const float* __restrict__ pvec,
                const float* __restrict__ Wg,
                const float* __restrict__ bg,
                const int* __restrict__ ei,
                float* __restrict__ out)
{
    __shared__ float4 Blo[NPGC];               //  8 KB node-major features ch 0-3
    __shared__ float4 Bhi[NPGC];               //  8 KB node-major features ch 4-7
    __shared__ u16    adjl[EPGC];              //  8 KB CSR adjacency (src per in-edge)
    __shared__ u16    indptr[NPGC + 2];        //  ~1 KB CSR row pointers
    __shared__ float  maskf[NPGC];             //  2 KB
    __shared__ float  degv[NPGC];              //  2 KB dinv; later comp16+chmax
    __shared__ __align__(16) ull keyv[NPGC];   //  4 KB rank records; P7: r1/r2
    __shared__ u32    hist[NPGC];              //  2 KB histogram / cum
    __shared__ u32    hoff[NPGC];              //  2 KB placement offsets
    __shared__ u32    wsum8[8];                //  32 B cross-wave prefix
    // total ~37.2 KB -> 4 blocks/CU

    const int tid  = threadIdx.x;
    const int lane = tid & 63;      // attention channel
    const int grp  = tid >> 6;      // wave id (0..7)
    const int g    = blockIdx.x;

    u16*   comp16 = reinterpret_cast<u16*>(degv);   // bytes [0,1024)
    float* chmax  = degv + 256;                     // bytes [1024,1280)
    float* r1 = reinterpret_cast<float*>(keyv);     // [8][64]
    float* r2 = r1 + 512;                           // [8][64]

    float wgc[8];
#pragma unroll
    for (int j = 0; j < 8; ++j) wgc[j] = Wg[j * 64 + lane];
    const float bgc = bg[lane];

    // ---- preload this thread's 8 edges, packed (src | dst<<16), local ids
    uint32_t er[8];
    {
        const int* rowp = ei;
        const int* colp = ei + ETOT;
        const size_t eb = (size_t)g * EPGC + (size_t)tid * 8;
#pragma unroll
        for (int i = 0; i < 2; ++i) {
            int4 r4 = *reinterpret_cast<const int4*>(rowp + eb + i * 4);
            int4 c4 = *reinterpret_cast<const int4*>(colp + eb + i * 4);
            er[i * 4 + 0] = (uint32_t)(r4.x & 511) | ((uint32_t)(c4.x & 511) << 16);
            er[i * 4 + 1] = (uint32_t)(r4.y & 511) | ((uint32_t)(c4.y & 511) << 16);
            er[i * 4 + 2] = (uint32_t)(r4.z & 511) | ((uint32_t)(c4.z & 511) << 16);
            er[i * 4 + 3] = (uint32_t)(r4.w & 511) | ((uint32_t)(c4.w & 511) << 16);
        }
    }

    // ---- load x into node-major B, mask = 1
    {
        const float* xr = x + ((size_t)g * NPGC + tid) * 8;
        Blo[tid] = *reinterpret_cast<const float4*>(xr);
        Bhi[tid] = *reinterpret_cast<const float4*>(xr + 4);
        maskf[tid] = 1.0f;
    }
    hist[tid] = 0u;
    __syncthreads();

    // ---- build in-edge CSR once (edge list is layer-invariant)
#pragma unroll
    for (int i = 0; i < 8; ++i) atomicAdd(&hist[er[i] >> 16], 1u);
    __syncthreads();
    {
        const u32 hv = hist[tid];
        u32 sc = hv;
#pragma unroll
        for (int d = 1; d < 64; d <<= 1) {
            const u32 t = __shfl_up(sc, (unsigned)d, 64);
            if (lane >= d) sc += t;
        }
        if (lane == 63) wsum8[grp] = sc;
        __syncthreads();
        u32 woff = 0;
#pragma unroll
        for (int w = 0; w < 7; ++w) woff += (w < grp) ? wsum8[w] : 0u;
        const u32 excl = sc + woff - hv;
        indptr[tid] = (u16)excl;
        hoff[tid]   = excl;
        if (tid == NPGC - 1) indptr[NPGC] = (u16)(excl + hv);
    }
    __syncthreads();
#pragma unroll
    for (int i = 0; i < 8; ++i) {
        const u32 d = er[i] >> 16, s = er[i] & 0xffffu;
        const u32 pos = atomicAdd(&hoff[d], 1u);
        adjl[pos] = (u16)s;
    }
    // (layer-top barrier covers adjl visibility)

    int   kkprev  = NPGC;
    float out_acc = 0.f;

#pragma unroll 1
    for (int layer = 0; layer < 4; ++layer) {
        const float* Wl = Wc + layer * 64;
        const float* bl = bc + layer * 8;
        const float* pl = pvec + layer * 8;
        const int kk = (layer == 0) ? 410 : (layer == 1) ? 328 : (layer == 2) ? 263 : 211;

        __syncthreads();
        const float mf = maskf[tid];
        const int ib = indptr[tid], ie = indptr[tid + 1];

        // ---- P1: matvec (B <- h@W, own slot) + degree gather (no atomics)
        float dg = mf;
        if (mf > 0.f) {
            const float4 lo = Blo[tid], hi = Bhi[tid];
            const float hv8[8] = {lo.x, lo.y, lo.z, lo.w, hi.x, hi.y, hi.z, hi.w};
            float yv[8];
#pragma unroll
            for (int k = 0; k < 8; ++k) {
                float acc = 0.f;
#pragma unroll
                for (int j = 0; j < 8; ++j) acc += hv8[j] * Wl[j * 8 + k];
                yv[k] = acc;
            }
            Blo[tid] = make_float4(yv[0], yv[1], yv[2], yv[3]);
            Bhi[tid] = make_float4(yv[4], yv[5], yv[6], yv[7]);
            for (int j = ib; j < ie; ++j) dg += maskf[adjl[j]];
        }
        degv[tid] = (dg > 0.f) ? rsqrtf(dg) : 0.f;   // 0 encodes invalid
        __syncthreads();

        // ---- P2: register gather (conv) + P4 fused (bias/relu/score/key)
        float v0 = 0.f, v1 = 0.f, v2 = 0.f, v3 = 0.f,
              v4 = 0.f, v5 = 0.f, v6 = 0.f, v7 = 0.f;
        float s0 = 0.f;
        int bin0 = 0;
        ull rec0 = 0;
        if (mf > 0.f) {
            const float di = degv[tid];
            const float c0 = di * di;
            const float4 lo = Blo[tid], hi = Bhi[tid];
            float a0 = lo.x * c0, a1 = lo.y * c0, a2 = lo.z * c0, a3 = lo.w * c0;
            float a4 = hi.x * c0, a5 = hi.y * c0, a6 = hi.z * c0, a7 = hi.w * c0;
            for (int j = ib; j < ie; ++j) {
                const int s = adjl[j];
                const float w2 = degv[s] * di;       // 0 for invalid neighbors
                const float4 slo = Blo[s], shi = Bhi[s];
                a0 += slo.x * w2; a1 += slo.y * w2; a2 += slo.z * w2; a3 += slo.w * w2;
                a4 += shi.x * w2; a5 += shi.y * w2; a6 += shi.z * w2; a7 += shi.w * w2;
            }
            float pv[8], ss = 0.f;
#pragma unroll
            for (int k = 0; k < 8; ++k) { pv[k] = pl[k]; ss += pv[k] * pv[k]; }
            const float pn = sqrtf(ss);
            float dot = 0.f;
            v0 = fmaxf(a0 + bl[0], 0.f); dot += v0 * pv[0];
            v1 = fmaxf(a1 + bl[1], 0.f); dot += v1 * pv[1];
            v2 = fmaxf(a2 + bl[2], 0.f); dot += v2 * pv[2];
            v3 = fmaxf(a3 + bl[3], 0.f); dot += v3 * pv[3];
            v4 = fmaxf(a4 + bl[4], 0.f); dot += v4 * pv[4];
            v5 = fmaxf(a5 + bl[5], 0.f); dot += v5 * pv[5];
            v6 = fmaxf(a6 + bl[6], 0.f); dot += v6 * pv[6];
            v7 = fmaxf(a7 + bl[7], 0.f); dot += v7 * pv[7];
            s0 = tanhf(dot / pn);
            const unsigned ub  = __float_as_uint(s0);
            const unsigned asc = (ub & 0x80000000u) ? ~ub : (ub | 0x80000000u);
            rec0 = ((ull)(~asc) << 32) | (u32)tid;   // desc score, ties idx asc
            int b = (int)((1.0f - s0) * 256.0f);     // monotone with key
            bin0 = (b < 0) ? 0 : ((b > 511) ? 511 : b);
        }
        hist[tid] = 0u;                  // hist/hoff free here (no reader this phase)
        hoff[tid] = 0u;
        __syncthreads();                 // gathers complete; hist cleared

        // ---- P5: exact histogram rank
        if (mf > 0.f) atomicAdd(&hist[bin0], 1u);
        __syncthreads();
        {
            const u32 hv = hist[tid];
            u32 sc = hv;
#pragma unroll
            for (int d = 1; d < 64; d <<= 1) {
                const u32 t = __shfl_up(sc, (unsigned)d, 64);
                if (lane >= d) sc += t;
            }
            if (lane == 63) wsum8[grp] = sc;
            __syncthreads();
            u32 woff = 0;
#pragma unroll
            for (int w = 0; w < 7; ++w) woff += (w < grp) ? wsum8[w] : 0u;
            hist[tid] = sc + woff - hv;  // exclusive cum (own slot)
        }
        __syncthreads();
        u32 base = 0, nxt = 0;
        if (mf > 0.f) {
            base = hist[bin0];
            nxt  = (bin0 < 511) ? hist[bin0 + 1] : (u32)kkprev;
            const u32 pos = base + atomicAdd(&hoff[bin0], 1u);
            keyv[pos] = rec0;            // in-bin order irrelevant (counted below)
        }
        __syncthreads();
        u32 rank = 0xFFFFFFFFu;
        if (mf > 0.f) {
            u32 r = base;
            for (u32 j = base; j < nxt; ++j) r += (keyv[j] < rec0) ? 1u : 0u;
            rank = r;
        }

        // ---- P6: keep top-k; write only kept nodes' scaled features
        if (mf > 0.f) {
            if (rank < (u32)kk) {
                comp16[rank] = (u16)tid;
                Blo[tid] = make_float4(v0 * s0, v1 * s0, v2 * s0, v3 * s0);
                Bhi[tid] = make_float4(v4 * s0, v5 * s0, v6 * s0, v7 * s0);
            } else {
                maskf[tid] = 0.f;        // stale B never read (dinv/comp gating)
            }
        }
        __syncthreads();

        // ---- P7: attention pool, online softmax, 2-way ILP
        {
            float m = NEGF, esum = 0.f, wsum2 = 0.f;
            int i = grp;
            for (; i + 8 < kk; i += 16) {
                const int na = comp16[i];
                const int nb = comp16[i + 8];
                const float4 alo = Blo[na], ahi = Bhi[na];   // broadcast b128
                const float4 blo = Blo[nb], bhi = Bhi[nb];
                float ga = bgc, gb = bgc;
                ga += alo.x * wgc[0] + alo.y * wgc[1] + alo.z * wgc[2] + alo.w * wgc[3];
                ga += ahi.x * wgc[4] + ahi.y * wgc[5] + ahi.z * wgc[6] + ahi.w * wgc[7];
                gb += blo.x * wgc[0] + blo.y * wgc[1] + blo.z * wgc[2] + blo.w * wgc[3];
                gb += bhi.x * wgc[4] + bhi.y * wgc[5] + bhi.z * wgc[6] + bhi.w * wgc[7];
                const float mn = fmaxf(m, fmaxf(ga, gb));
                const float sc = __expf(m - mn);
                const float ea = __expf(ga - mn);
                const float eb = __expf(gb - mn);
                esum  = esum * sc + ea + eb;
                wsum2 = wsum2 * sc + ea * ga + eb * gb;
                m = mn;
            }
            if (i < kk) {
                const int na = comp16[i];
                const float4 alo = Blo[na], ahi = Bhi[na];
                float ga = bgc;
                ga += alo.x * wgc[0] + alo.y * wgc[1] + alo.z * wgc[2] + alo.w * wgc[3];
                ga += ahi.x * wgc[4] + ahi.y * wgc[5] + ahi.z * wgc[6] + ahi.w * wgc[7];
                const float mn = fmaxf(m, ga);
                const float sc = __expf(m - mn);
                const float ea = __expf(ga - mn);
                esum  = esum * sc + ea;
                wsum2 = wsum2 * sc + ea * ga;
                m = mn;
            }
            r1[grp * 64 + lane] = m;
            __syncthreads();
            if (tid < 64) {
                float M = r1[tid];
#pragma unroll
                for (int w = 1; w < 8; ++w) M = fmaxf(M, r1[w * 64 + tid]);
                chmax[tid] = M;
            }
            __syncthreads();
            const float M  = chmax[lane];
            const float sc = __expf(m - M);
            r1[grp * 64 + lane] = esum * sc;
            r2[grp * 64 + lane] = wsum2 * sc;
            __syncthreads();
            if (tid < 64) {
                float es = 0.f, ws = 0.f;
#pragma unroll
                for (int w = 0; w < 8; ++w) { es += r1[w * 64 + tid]; ws += r2[w * 64 + tid]; }
                out_acc += ws / es;
            }
        }

        kkprev = kk;
    }

    if (tid < 64) out[(size_t)g * 64 + tid] = out_acc;
}

extern "C" void kernel_launch(void* const* d_in, const int* in_sizes, int n_in,
                              void* d_out, int out_size, void* d_ws, size_t ws_size,
                              hipStream_t stream) {
    const float* x    = (const float*)d_in[0];
    const float* Wc   = (const float*)d_in[1];
    const float* bc   = (const float*)d_in[2];
    const float* pvec = (const float*)d_in[3];
    const float* Wg   = (const float*)d_in[4];
    const float* bg   = (const float*)d_in[5];
    const int*   ei   = (const int*)d_in[6];
    float* out = (float*)d_out;

    gce_kernel<<<dim3(1024), dim3(NTHREADS), 0, stream>>>(x, Wc, bc, pvec, Wg, bg, ei, out);
}

// Round 8
// 143.921 us; speedup vs baseline: 4.0288x; 1.0695x over previous
//
#include <hip/hip_runtime.h>
#include <stdint.h>

typedef unsigned long long ull;
typedef unsigned int u32;
typedef unsigned short u16;

#define NPGC 512
#define EPGC 4096
#define NTHREADS 512
#define ETOT 4194304

__global__ __launch_bounds__(NTHREADS, 6)
void gce_kernel(const float* __restrict__ x,
                const float* __restrict__ Wc,
                const float* __restrict__ bc,
                const float* __restrict__ pvec,
                const float* __restrict__ Wg,
                const float* __restrict__ bg,
                const int* __restrict__ ei,
                float* __restrict__ out)
{
    __shared__ float4 Blo[NPGC];               //  8 KB node features ch 0-3 (h' = h*dinv in gather phase)
    __shared__ float4 Bhi[NPGC];               //  8 KB node features ch 4-7
    __shared__ u16    adjl[EPGC];              //  8 KB CSR adjacency (src per in-edge)
    __shared__ u16    indptr[NPGC + 2];        //  ~1 KB CSR row pointers
    __shared__ float  maskf[NPGC];             //  2 KB validity
    __shared__ u16    comp16[NPGC];            //  1 KB compacted kept-node list
    __shared__ __align__(16) ull keyv[NPGC];   //  4 KB rank records; P7: r1/r2
    __shared__ u32    hist[NPGC];              //  2 KB histogram / cum
    __shared__ u32    hoff[NPGC];              //  2 KB placement offsets
    __shared__ u32    wsum8[8];                //  32 B cross-wave prefix
    // total ~36.1 KB -> 4 blocks/CU

    const int tid  = threadIdx.x;
    const int lane = tid & 63;      // attention channel
    const int grp  = tid >> 6;      // wave id (0..7)
    const int g    = blockIdx.x;

    float* r1 = reinterpret_cast<float*>(keyv);     // [8][64]
    float* r2 = r1 + 512;                           // [8][64]

    float wgc[8];
#pragma unroll
    for (int j = 0; j < 8; ++j) wgc[j] = Wg[j * 64 + lane];
    const float bgc = bg[lane];

    // ---- preload this thread's 8 edges, packed (src | dst<<16), local ids
    uint32_t er[8];
    {
        const int* rowp = ei;
        const int* colp = ei + ETOT;
        const size_t eb = (size_t)g * EPGC + (size_t)tid * 8;
#pragma unroll
        for (int i = 0; i < 2; ++i) {
            int4 r4 = *reinterpret_cast<const int4*>(rowp + eb + i * 4);
            int4 c4 = *reinterpret_cast<const int4*>(colp + eb + i * 4);
            er[i * 4 + 0] = (uint32_t)(r4.x & 511) | ((uint32_t)(c4.x & 511) << 16);
            er[i * 4 + 1] = (uint32_t)(r4.y & 511) | ((uint32_t)(c4.y & 511) << 16);
            er[i * 4 + 2] = (uint32_t)(r4.z & 511) | ((uint32_t)(c4.z & 511) << 16);
            er[i * 4 + 3] = (uint32_t)(r4.w & 511) | ((uint32_t)(c4.w & 511) << 16);
        }
    }

    // ---- load x into node-major B, mask = 1
    {
        const float* xr = x + ((size_t)g * NPGC + tid) * 8;
        Blo[tid] = *reinterpret_cast<const float4*>(xr);
        Bhi[tid] = *reinterpret_cast<const float4*>(xr + 4);
        maskf[tid] = 1.0f;
    }
    hist[tid] = 0u;
    __syncthreads();

    // ---- build in-edge CSR once (edge list is layer-invariant)
#pragma unroll
    for (int i = 0; i < 8; ++i) atomicAdd(&hist[er[i] >> 16], 1u);
    __syncthreads();
    {
        const u32 hv = hist[tid];
        u32 sc = hv;
#pragma unroll
        for (int d = 1; d < 64; d <<= 1) {
            const u32 t = __shfl_up(sc, (unsigned)d, 64);
            if (lane >= d) sc += t;
        }
        if (lane == 63) wsum8[grp] = sc;
        __syncthreads();
        u32 woff = 0;
#pragma unroll
        for (int w = 0; w < 7; ++w) woff += (w < grp) ? wsum8[w] : 0u;
        const u32 excl = sc + woff - hv;
        indptr[tid] = (u16)excl;
        hoff[tid]   = excl;
        if (tid == NPGC - 1) indptr[NPGC] = (u16)(excl + hv);
    }
    __syncthreads();
#pragma unroll
    for (int i = 0; i < 8; ++i) {
        const u32 d = er[i] >> 16, s = er[i] & 0xffffu;
        const u32 pos = atomicAdd(&hoff[d], 1u);
        adjl[pos] = (u16)s;
    }
    // (layer-top barrier covers adjl visibility)

    int   kkprev  = NPGC;
    float out_acc = 0.f;

#pragma unroll 1
    for (int layer = 0; layer < 4; ++layer) {
        const float* Wl = Wc + layer * 64;
        const float* bl = bc + layer * 8;
        const float* pl = pvec + layer * 8;
        const int kk = (layer == 0) ? 410 : (layer == 1) ? 328 : (layer == 2) ? 263 : 211;

        __syncthreads();                         // B1: B/maskf stable; prev r1/r2/hist dead
        const float mf = maskf[tid];
        const int ib = indptr[tid], ie = indptr[tid + 1];

        // ---- Phase A: deg gather -> dinv (thread-local) ; B <- h*dinv (own slot)
        float dinv = 0.f;
        if (mf > 0.f) {
            float dg = mf;
            for (int j = ib; j < ie; ++j) dg += maskf[adjl[j]];
            dinv = rsqrtf(dg);                   // dg >= 1 for valid nodes
        }
        {
            float4 lo = Blo[tid], hi = Bhi[tid];
            lo.x *= dinv; lo.y *= dinv; lo.z *= dinv; lo.w *= dinv;
            hi.x *= dinv; hi.y *= dinv; hi.z *= dinv; hi.w *= dinv;
            Blo[tid] = lo; Bhi[tid] = hi;        // invalid -> exactly 0
        }
        hist[tid] = 0u;
        hoff[tid] = 0u;
        __syncthreads();                         // B2: h' visible, hist cleared

        // ---- Phase B: pure-add gather; agg*dinv @ W; bias/relu/score/key
        float v0 = 0.f, v1 = 0.f, v2 = 0.f, v3 = 0.f,
              v4 = 0.f, v5 = 0.f, v6 = 0.f, v7 = 0.f;
        float s0 = 0.f;
        int bin0 = 0;
        ull rec0 = 0;
        if (mf > 0.f) {
            const float4 alo = Blo[tid], ahi = Bhi[tid];   // self (weight dinv folds below)
            float a0 = alo.x, a1 = alo.y, a2 = alo.z, a3 = alo.w;
            float a4 = ahi.x, a5 = ahi.y, a6 = ahi.z, a7 = ahi.w;
            for (int j = ib; j < ie; ++j) {
                const int s = adjl[j];
                const float4 slo = Blo[s], shi = Bhi[s];   // invalid s contribute 0
                a0 += slo.x; a1 += slo.y; a2 += slo.z; a3 += slo.w;
                a4 += shi.x; a5 += shi.y; a6 += shi.z; a7 += shi.w;
            }
            a0 *= dinv; a1 *= dinv; a2 *= dinv; a3 *= dinv;
            a4 *= dinv; a5 *= dinv; a6 *= dinv; a7 *= dinv;
            const float av[8] = {a0, a1, a2, a3, a4, a5, a6, a7};
            float yv[8];
#pragma unroll
            for (int k = 0; k < 8; ++k) {
                float acc = 0.f;
#pragma unroll
                for (int j = 0; j < 8; ++j) acc += av[j] * Wl[j * 8 + k];
                yv[k] = acc;
            }
            float pv[8], ss = 0.f;
#pragma unroll
            for (int k = 0; k < 8; ++k) { pv[k] = pl[k]; ss += pv[k] * pv[k]; }
            float dot = 0.f;
            v0 = fmaxf(yv[0] + bl[0], 0.f); dot += v0 * pv[0];
            v1 = fmaxf(yv[1] + bl[1], 0.f); dot += v1 * pv[1];
            v2 = fmaxf(yv[2] + bl[2], 0.f); dot += v2 * pv[2];
            v3 = fmaxf(yv[3] + bl[3], 0.f); dot += v3 * pv[3];
            v4 = fmaxf(yv[4] + bl[4], 0.f); dot += v4 * pv[4];
            v5 = fmaxf(yv[5] + bl[5], 0.f); dot += v5 * pv[5];
            v6 = fmaxf(yv[6] + bl[6], 0.f); dot += v6 * pv[6];
            v7 = fmaxf(yv[7] + bl[7], 0.f); dot += v7 * pv[7];
            s0 = tanhf(dot / sqrtf(ss));
            const unsigned ub  = __float_as_uint(s0);
            const unsigned asc = (ub & 0x80000000u) ? ~ub : (ub | 0x80000000u);
            rec0 = ((ull)(~asc) << 32) | (u32)tid;   // desc score, ties idx asc
            int b = (int)((1.0f - s0) * 256.0f);     // monotone with key
            bin0 = (b < 0) ? 0 : ((b > 511) ? 511 : b);
            atomicAdd(&hist[bin0], 1u);
        }
        __syncthreads();                         // B3: histogram complete

        // ---- P5: exclusive prefix-sum over 512 bins
        {
            const u32 hv = hist[tid];
            u32 sc = hv;
#pragma unroll
            for (int d = 1; d < 64; d <<= 1) {
                const u32 t = __shfl_up(sc, (unsigned)d, 64);
                if (lane >= d) sc += t;
            }
            if (lane == 63) wsum8[grp] = sc;
            __syncthreads();                     // B4
            u32 woff = 0;
#pragma unroll
            for (int w = 0; w < 7; ++w) woff += (w < grp) ? wsum8[w] : 0u;
            hist[tid] = sc + woff - hv;          // exclusive cum (own slot)
        }
        __syncthreads();                         // B5: cum ready

        u32 base = 0, nxt = 0;
        if (mf > 0.f) {
            base = hist[bin0];
            nxt  = (bin0 < 511) ? hist[bin0 + 1] : (u32)kkprev;
            const u32 pos = base + atomicAdd(&hoff[bin0], 1u);
            keyv[pos] = rec0;                    // in-bin order irrelevant (counted)
        }
        __syncthreads();                         // B6: records placed

        u32 rank = 0xFFFFFFFFu;
        if (mf > 0.f) {
            u32 r = base;
            for (u32 j = base; j < nxt; ++j) r += (keyv[j] < rec0) ? 1u : 0u;
            rank = r;
        }

        // ---- P6: keep top-k; write kept nodes' scaled features + compacted list
        if (mf > 0.f) {
            if (rank < (u32)kk) {
                comp16[rank] = (u16)tid;
                Blo[tid] = make_float4(v0 * s0, v1 * s0, v2 * s0, v3 * s0);
                Bhi[tid] = make_float4(v4 * s0, v5 * s0, v6 * s0, v7 * s0);
            } else {
                maskf[tid] = 0.f;
                Blo[tid] = make_float4(0.f, 0.f, 0.f, 0.f);   // keep B clean (was h*dinv)
                Bhi[tid] = make_float4(0.f, 0.f, 0.f, 0.f);
            }
        }
        __syncthreads();                         // B7: comp16 + scaled B ready

        // ---- P7: attention pool, shift-free softmax (constant shift cancels in ws/es)
        {
            float esum = 0.f, wsum2 = 0.f;
#pragma unroll 2
            for (int i = grp; i < kk; i += 8) {
                const int n = comp16[i];                    // wave-uniform
                const float4 lo = Blo[n], hi = Bhi[n];      // broadcast b128
                float gv = bgc;
                gv += lo.x * wgc[0] + lo.y * wgc[1] + lo.z * wgc[2] + lo.w * wgc[3];
                gv += hi.x * wgc[4] + hi.y * wgc[5] + hi.z * wgc[6] + hi.w * wgc[7];
                const float e = __expf(gv);
                esum += e;
                wsum2 = fmaf(e, gv, wsum2);
            }
            r1[grp * 64 + lane] = esum;
            r2[grp * 64 + lane] = wsum2;
            __syncthreads();                     // B8: partials ready
            if (tid < 64) {
                float es = 0.f, ws = 0.f;
#pragma unroll
                for (int w = 0; w < 8; ++w) { es += r1[w * 64 + tid]; ws += r2[w * 64 + tid]; }
                out_acc += ws / es;
            }
        }

        kkprev = kk;
    }

    if (tid < 64) out[(size_t)g * 64 + tid] = out_acc;
}

extern "C" void kernel_launch(void* const* d_in, const int* in_sizes, int n_in,
                              void* d_out, int out_size, void* d_ws, size_t ws_size,
                              hipStream_t stream) {
    const float* x    = (const float*)d_in[0];
    const float* Wc   = (const float*)d_in[1];
    const float* bc   = (const float*)d_in[2];
    const float* pvec = (const float*)d_in[3];
    const float* Wg   = (const float*)d_in[4];
    const float* bg   = (const float*)d_in[5];
    const int*   ei   = (const int*)d_in[6];
    float* out = (float*)d_out;

    gce_kernel<<<dim3(1024), dim3(NTHREADS), 0, stream>>>(x, Wc, bc, pvec, Wg, bg, ei, out);
}

// Round 9
// 137.475 us; speedup vs baseline: 4.2177x; 1.0469x over previous
//
#include <hip/hip_runtime.h>
#include <stdint.h>

typedef unsigned long long ull;
typedef unsigned int u32;
typedef unsigned short u16;

#define NPGC 512
#define EPGC 4096
#define NTHREADS 512
#define ETOT 4194304
#define ADJMAX (EPGC + 3 * NPGC / 2 + NPGC)   // 4096 + worst-case pad (3/row) = 5632, rounded up

__global__ __launch_bounds__(NTHREADS, 6)
void gce_kernel(const float* __restrict__ x,
                const float* __restrict__ Wc,
                const float* __restrict__ bc,
                const float* __restrict__ pvec,
                const float* __restrict__ Wg,
                const float* __restrict__ bg,
                const int* __restrict__ ei,
                float* __restrict__ out)
{
    __shared__ float4 Clo[NPGC + 1];            // 8208 B compacted features ch0-3; slot 512 = zeros
    __shared__ float4 Chi[NPGC + 1];            // 8208 B compacted features ch4-7
    __shared__ __align__(8) u16 adjl[5632];     // 11264 B padded CSR (ORIGINAL src ids; pad=512)
    __shared__ u16    indptr[NPGC + 1];         // 1026 B padded row offsets (by original id)
    __shared__ u16    slotof[NPGC + 1];         // 1026 B original id -> current slot (512 = dropped)
    __shared__ u16    orig16[NPGC];             // 1024 B current slot -> original id
    __shared__ __align__(16) ull keyv[NPGC];    // 4096 B rank records; P7: r1/r2
    __shared__ u32    hist[NPGC];               // 2048 B histogram / cum
    __shared__ u32    hoff[NPGC];               // 2048 B placement offsets
    __shared__ u32    wsum8[8];                 // 32 B cross-wave prefix
    // total 38980 B -> 4 blocks/CU

    const int tid  = threadIdx.x;
    const int lane = tid & 63;      // attention channel
    const int grp  = tid >> 6;      // wave id (0..7)
    const int g    = blockIdx.x;

    float* r1 = reinterpret_cast<float*>(keyv); // [8][64]
    float* r2 = r1 + 512;                       // [8][64]

    float wgc[8];
#pragma unroll
    for (int j = 0; j < 8; ++j) wgc[j] = Wg[j * 64 + lane];
    const float bgc = bg[lane];

    // ---- preload this thread's 8 edges, packed (src | dst<<16), local ids
    uint32_t er[8];
    {
        const int* rowp = ei;
        const int* colp = ei + ETOT;
        const size_t eb = (size_t)g * EPGC + (size_t)tid * 8;
#pragma unroll
        for (int i = 0; i < 2; ++i) {
            int4 r4 = *reinterpret_cast<const int4*>(rowp + eb + i * 4);
            int4 c4 = *reinterpret_cast<const int4*>(colp + eb + i * 4);
            er[i * 4 + 0] = (uint32_t)(r4.x & 511) | ((uint32_t)(c4.x & 511) << 16);
            er[i * 4 + 1] = (uint32_t)(r4.y & 511) | ((uint32_t)(c4.y & 511) << 16);
            er[i * 4 + 2] = (uint32_t)(r4.z & 511) | ((uint32_t)(c4.z & 511) << 16);
            er[i * 4 + 3] = (uint32_t)(r4.w & 511) | ((uint32_t)(c4.w & 511) << 16);
        }
    }

    // ---- init: features (slot = orig at layer 0), identity maps, zero slot
    {
        const float* xr = x + ((size_t)g * NPGC + tid) * 8;
        Clo[tid] = *reinterpret_cast<const float4*>(xr);
        Chi[tid] = *reinterpret_cast<const float4*>(xr + 4);
        slotof[tid] = (u16)tid;
        orig16[tid] = (u16)tid;
        hist[tid] = 0u;
        if (tid == 0) {
            slotof[NPGC] = (u16)NPGC;
            Clo[NPGC] = make_float4(0.f, 0.f, 0.f, 0.f);
            Chi[NPGC] = make_float4(0.f, 0.f, 0.f, 0.f);
        }
    }
    __syncthreads();

    // ---- build padded in-edge CSR once (rows 4-aligned, tail-padded with id 512)
#pragma unroll
    for (int i = 0; i < 8; ++i) atomicAdd(&hist[er[i] >> 16], 1u);
    __syncthreads();
    {
        const u32 hv  = hist[tid];
        const u32 hvp = (hv + 3u) & ~3u;        // padded row length
        u32 sc = hvp;
#pragma unroll
        for (int d = 1; d < 64; d <<= 1) {
            const u32 t = __shfl_up(sc, (unsigned)d, 64);
            if (lane >= d) sc += t;
        }
        if (lane == 63) wsum8[grp] = sc;
        __syncthreads();
        u32 woff = 0;
#pragma unroll
        for (int w = 0; w < 7; ++w) woff += (w < grp) ? wsum8[w] : 0u;
        const u32 excl = sc + woff - hvp;
        indptr[tid] = (u16)excl;
        hoff[tid]   = excl;
        if (tid == NPGC - 1) indptr[NPGC] = (u16)(excl + hvp);
    }
    __syncthreads();
#pragma unroll
    for (int i = 0; i < 8; ++i) {
        const u32 d = er[i] >> 16, s = er[i] & 0xffffu;
        const u32 pos = atomicAdd(&hoff[d], 1u);
        adjl[pos] = (u16)s;                     // ORIGINAL src id
    }
    __syncthreads();
    for (u32 j = hoff[tid]; j < (u32)indptr[tid + 1]; ++j) adjl[j] = (u16)NPGC;  // pad tail

    int   kkprev  = NPGC;
    float out_acc = 0.f;

#pragma unroll 1
    for (int layer = 0; layer < 4; ++layer) {
        const float* Wl = Wc + layer * 64;
        const float* bl = bc + layer * 8;
        const float* pl = pvec + layer * 8;
        const int kk = (layer == 0) ? 410 : (layer == 1) ? 328 : (layer == 2) ? 263 : 211;

        __syncthreads();                        // B1: adjl pads (L0) / prev layer done
        const bool valid = tid < kkprev;
        int me = 0, ib = 0, ie = 0;
        float dinv = 0.f;
        float4 slo = make_float4(0.f, 0.f, 0.f, 0.f), shi = slo;

        // ---- Phase A: deg via slot_of (no mask array) ; scale own features in place
        if (valid) {
            me = orig16[tid];
            ib = indptr[me];
            ie = indptr[me + 1];
            int dg = 1;                          // self-loop
            for (int j = ib; j < ie; j += 4) {
                const ushort4 q = *reinterpret_cast<const ushort4*>(&adjl[j]);
                dg += (slotof[q.x] != NPGC) + (slotof[q.y] != NPGC)
                    + (slotof[q.z] != NPGC) + (slotof[q.w] != NPGC);
            }
            dinv = rsqrtf((float)dg);
            slo = Clo[tid]; shi = Chi[tid];
            slo.x *= dinv; slo.y *= dinv; slo.z *= dinv; slo.w *= dinv;
            shi.x *= dinv; shi.y *= dinv; shi.z *= dinv; shi.w *= dinv;
            Clo[tid] = slo; Chi[tid] = shi;      // h' = h * dinv
        }
        hist[tid] = 0u;
        hoff[tid] = 0u;
        __syncthreads();                        // B2: h' visible, hist cleared

        // ---- Phase B: blind-add gather (dropped -> zero slot); @W; relu/score/key
        float v0 = 0.f, v1 = 0.f, v2 = 0.f, v3 = 0.f,
              v4 = 0.f, v5 = 0.f, v6 = 0.f, v7 = 0.f;
        float s0 = 0.f;
        int bin0 = 0;
        ull rec0 = 0;
        if (valid) {
            float a0 = slo.x, a1 = slo.y, a2 = slo.z, a3 = slo.w;
            float a4 = shi.x, a5 = shi.y, a6 = shi.z, a7 = shi.w;
            for (int j = ib; j < ie; j += 4) {
                const ushort4 q = *reinterpret_cast<const ushort4*>(&adjl[j]);
                const int t0 = slotof[q.x], t1 = slotof[q.y];
                const int t2 = slotof[q.z], t3 = slotof[q.w];
                const float4 l0 = Clo[t0], h0 = Chi[t0];
                const float4 l1 = Clo[t1], h1 = Chi[t1];
                const float4 l2 = Clo[t2], h2 = Chi[t2];
                const float4 l3 = Clo[t3], h3 = Chi[t3];
                a0 += (l0.x + l1.x) + (l2.x + l3.x);
                a1 += (l0.y + l1.y) + (l2.y + l3.y);
                a2 += (l0.z + l1.z) + (l2.z + l3.z);
                a3 += (l0.w + l1.w) + (l2.w + l3.w);
                a4 += (h0.x + h1.x) + (h2.x + h3.x);
                a5 += (h0.y + h1.y) + (h2.y + h3.y);
                a6 += (h0.z + h1.z) + (h2.z + h3.z);
                a7 += (h0.w + h1.w) + (h2.w + h3.w);
            }
            a0 *= dinv; a1 *= dinv; a2 *= dinv; a3 *= dinv;
            a4 *= dinv; a5 *= dinv; a6 *= dinv; a7 *= dinv;
            const float av[8] = {a0, a1, a2, a3, a4, a5, a6, a7};
            float yv[8];
#pragma unroll
            for (int k = 0; k < 8; ++k) {
                float acc = 0.f;
#pragma unroll
                for (int j = 0; j < 8; ++j) acc += av[j] * Wl[j * 8 + k];
                yv[k] = acc;
            }
            float pv[8], ss = 0.f;
#pragma unroll
            for (int k = 0; k < 8; ++k) { pv[k] = pl[k]; ss += pv[k] * pv[k]; }
            float dot = 0.f;
            v0 = fmaxf(yv[0] + bl[0], 0.f); dot += v0 * pv[0];
            v1 = fmaxf(yv[1] + bl[1], 0.f); dot += v1 * pv[1];
            v2 = fmaxf(yv[2] + bl[2], 0.f); dot += v2 * pv[2];
            v3 = fmaxf(yv[3] + bl[3], 0.f); dot += v3 * pv[3];
            v4 = fmaxf(yv[4] + bl[4], 0.f); dot += v4 * pv[4];
            v5 = fmaxf(yv[5] + bl[5], 0.f); dot += v5 * pv[5];
            v6 = fmaxf(yv[6] + bl[6], 0.f); dot += v6 * pv[6];
            v7 = fmaxf(yv[7] + bl[7], 0.f); dot += v7 * pv[7];
            s0 = tanhf(dot / sqrtf(ss));
            const unsigned ub  = __float_as_uint(s0);
            const unsigned asc = (ub & 0x80000000u) ? ~ub : (ub | 0x80000000u);
            rec0 = ((ull)(~asc) << 32) | (u32)me;    // desc score; ties by ORIGINAL id asc
            int b = (int)((1.0f - s0) * 256.0f);     // monotone with key
            bin0 = (b < 0) ? 0 : ((b > 511) ? 511 : b);
            atomicAdd(&hist[bin0], 1u);
        }
        __syncthreads();                        // B3: histogram complete

        // ---- P5: exclusive prefix-sum over 512 bins
        {
            const u32 hv = hist[tid];
            u32 sc = hv;
#pragma unroll
            for (int d = 1; d < 64; d <<= 1) {
                const u32 t = __shfl_up(sc, (unsigned)d, 64);
                if (lane >= d) sc += t;
            }
            if (lane == 63) wsum8[grp] = sc;
            __syncthreads();                    // B4
            u32 woff = 0;
#pragma unroll
            for (int w = 0; w < 7; ++w) woff += (w < grp) ? wsum8[w] : 0u;
            hist[tid] = sc + woff - hv;         // exclusive cum (own slot)
        }
        __syncthreads();                        // B5: cum ready

        u32 base = 0, nxt = 0;
        if (valid) {
            base = hist[bin0];
            nxt  = (bin0 < 511) ? hist[bin0 + 1] : (u32)kkprev;
            const u32 pos = base + atomicAdd(&hoff[bin0], 1u);
            keyv[pos] = rec0;                   // in-bin order irrelevant (counted)
        }
        __syncthreads();                        // B6: records placed

        u32 rank = 0xFFFFFFFFu;
        if (valid) {
            u32 r = base;
            for (u32 j = base; j < nxt; ++j) r += (keyv[j] < rec0) ? 1u : 0u;
            rank = r;
        }

        // ---- P6: in-place compaction permute (all reads of C/orig16/slotof done)
        if (valid) {
            if (rank < (u32)kk) {
                Clo[rank] = make_float4(v0 * s0, v1 * s0, v2 * s0, v3 * s0);
                Chi[rank] = make_float4(v4 * s0, v5 * s0, v6 * s0, v7 * s0);
                orig16[rank] = (u16)me;
                slotof[me]   = (u16)rank;
            } else {
                slotof[me] = (u16)NPGC;         // dropped -> zero slot
            }
        }
        __syncthreads();                        // B7: compacted C ready

        // ---- P7: attention pool over [0,kk): sequential broadcast reads, 2-way ILP
        {
            float e0 = 0.f, w0 = 0.f, e1 = 0.f, w1 = 0.f;
            int i = grp;
            for (; i + 8 < kk; i += 16) {
                const float4 la = Clo[i],     ha = Chi[i];
                const float4 lb = Clo[i + 8], hb = Chi[i + 8];
                float ga = bgc, gb = bgc;
                ga += la.x * wgc[0] + la.y * wgc[1] + la.z * wgc[2] + la.w * wgc[3];
                ga += ha.x * wgc[4] + ha.y * wgc[5] + ha.z * wgc[6] + ha.w * wgc[7];
                gb += lb.x * wgc[0] + lb.y * wgc[1] + lb.z * wgc[2] + lb.w * wgc[3];
                gb += hb.x * wgc[4] + hb.y * wgc[5] + hb.z * wgc[6] + hb.w * wgc[7];
                const float ea = __expf(ga);
                const float eb = __expf(gb);
                e0 += ea; w0 = fmaf(ea, ga, w0);
                e1 += eb; w1 = fmaf(eb, gb, w1);
            }
            if (i < kk) {
                const float4 la = Clo[i], ha = Chi[i];
                float ga = bgc;
                ga += la.x * wgc[0] + la.y * wgc[1] + la.z * wgc[2] + la.w * wgc[3];
                ga += ha.x * wgc[4] + ha.y * wgc[5] + ha.z * wgc[6] + ha.w * wgc[7];
                const float ea = __expf(ga);
                e0 += ea; w0 = fmaf(ea, ga, w0);
            }
            r1[grp * 64 + lane] = e0 + e1;
            r2[grp * 64 + lane] = w0 + w1;
            __syncthreads();                    // B8: partials ready
            if (tid < 64) {
                float es = 0.f, ws = 0.f;
#pragma unroll
                for (int w = 0; w < 8; ++w) { es += r1[w * 64 + tid]; ws += r2[w * 64 + tid]; }
                out_acc += ws / es;
            }
        }

        kkprev = kk;
    }

    if (tid < 64) out[(size_t)g * 64 + tid] = out_acc;
}

extern "C" void kernel_launch(void* const* d_in, const int* in_sizes, int n_in,
                              void* d_out, int out_size, void* d_ws, size_t ws_size,
                              hipStream_t stream) {
    const float* x    = (const float*)d_in[0];
    const float* Wc   = (const float*)d_in[1];
    const float* bc   = (const float*)d_in[2];
    const float* pvec = (const float*)d_in[3];
    const float* Wg   = (const float*)d_in[4];
    const float* bg   = (const float*)d_in[5];
    const int*   ei   = (const int*)d_in[6];
    float* out = (float*)d_out;

    gce_kernel<<<dim3(1024), dim3(NTHREADS), 0, stream>>>(x, Wc, bc, pvec, Wg, bg, ei, out);
}